// Round 3
// baseline (195.136 us; speedup 1.0000x reference)
//
#include <hip/hip_runtime.h>

#define N_NODES 50000
#define IN_DIM  256
#define OUT_DIM 128
#define OD2     64       // packed fp16 pairs per 128-dim row
#define NBINS   782      // bin = row >> 6  (64 rows per bin)
#define RPB     64
#define CHUNK   4096     // edges per partition block (round-10/12 proven)
#define EPT     16       // edges per thread in partition (CHUNK/256)
#define CAPBX   1408     // X edges per bin: mean 1024, +12 sigma
#define CAPBA   2600     // adj edges per bin: mean 2048, +12 sigma
#define CSTRIDE 8        // bin counters padded to one 32B sector
#define SBINS   512      // adj rowsort bins: row6 * 8 + col-phase3

typedef unsigned long long u64;
typedef _Float16 half2v __attribute__((ext_vector_type(2)));

// ---------------------------------------------------------------------------
// fp16 helpers.  Pack is RNE via scalar casts (epilogue-only, cost negligible);
// unpack relies on (float)h folding into v_fma_mix_f32 at the use site.
// ---------------------------------------------------------------------------
__device__ __forceinline__ unsigned pack_f16x2(float a, float b) {
    unsigned short ua = __builtin_bit_cast(unsigned short, (_Float16)a);
    unsigned short ub = __builtin_bit_cast(unsigned short, (_Float16)b);
    return (unsigned)ua | ((unsigned)ub << 16);
}

// Accumulate one edge (value v, packed fp16 quad p = 8 dims) into 8 output
// dims.  Each product is fma(v, fpext(f16), acc) -> v_fma_mix_f32.
__device__ __forceinline__ void acc_edge(uint4 p, float v, float4& A, float4& B) {
    half2v h0 = __builtin_bit_cast(half2v, p.x);
    half2v h1 = __builtin_bit_cast(half2v, p.y);
    half2v h2 = __builtin_bit_cast(half2v, p.z);
    half2v h3 = __builtin_bit_cast(half2v, p.w);
    A.x += v * (float)h0.x; A.y += v * (float)h0.y;
    A.z += v * (float)h1.x; A.w += v * (float)h1.y;
    B.x += v * (float)h2.x; B.y += v * (float)h2.y;
    B.z += v * (float)h3.x; B.w += v * (float)h3.y;
}

// Edge word (u64): [63:32] = f32 val bits, [31:16] = row, [15:0] = col.
// Packed edge (u32): [31:16] = bf16 val bits, [15:0] = col.

// ---------------------------------------------------------------------------
// Level 1: partition into 782 row-bins (proven version).  NEW: the LAST block
// of the grid converts W (f32) to fp16 Wh instead -- ready before k2 launches.
// ---------------------------------------------------------------------------
__global__ __launch_bounds__(256) void partition(
        const int* __restrict__ xr, const int* __restrict__ xc,
        const float* __restrict__ xv, const float* __restrict__ dn, int nnz,
        const int* __restrict__ ar, const int* __restrict__ ac,
        const float* __restrict__ av, int ne,
        int* __restrict__ gcur_x, u64* __restrict__ egx,
        int* __restrict__ gcur_a, u64* __restrict__ ega, int bx,
        const float2* __restrict__ Wsrc, unsigned* __restrict__ Wh) {
    __shared__ u64 stage[CHUNK];          // 32 KB
    __shared__ int hist[1024];            // zero-padded past NBINS
    __shared__ int base_l[1024];
    __shared__ int cur_l[1024];
    __shared__ int gbase[1024];
    __shared__ int tsum[256];

    int t = threadIdx.x;

    if (blockIdx.x == gridDim.x - 1) {
        // W f32 -> fp16 (RNE), 32768 elems = 16384 packed words
        for (int i = t; i < IN_DIM * OUT_DIM / 2; i += 256) {
            float2 wv = Wsrc[i];
            Wh[i] = pack_f16x2(wv.x, wv.y);
        }
        return;
    }

    const int *rows, *cols;
    const float *vals, *noise = nullptr;
    int n, c0, cap;
    int* gcur;
    u64* eg;
    if (blockIdx.x < bx) {
        rows = xr; cols = xc; vals = xv; noise = dn; n = nnz;
        c0 = blockIdx.x * CHUNK; gcur = gcur_x; eg = egx; cap = CAPBX;
    } else {
        rows = ar; cols = ac; vals = av; n = ne;
        c0 = (blockIdx.x - bx) * CHUNK; gcur = gcur_a; eg = ega; cap = CAPBA;
    }

    for (int i = t; i < 1024; i += 256) hist[i] = 0;
    __syncthreads();

    u64 w[EPT];
    bool ok[EPT];
    #pragma unroll
    for (int j = 0; j < EPT; ++j) {
        int i = c0 + j * 256 + t;
        ok[j] = (i < n);
        if (ok[j]) {
            int r = rows[i], c = cols[i];
            float v = vals[i];
            if (noise) v *= floorf(1.0f + noise[i]);
            w[j] = ((u64)__float_as_uint(v) << 32) | ((unsigned)r << 16) | (unsigned)c;
            atomicAdd(&hist[r >> 6], 1);
        }
    }
    __syncthreads();

    // exclusive scan of hist (1024 entries, 4/thread + Hillis-Steele)
    int s0 = hist[t * 4], s1 = hist[t * 4 + 1], s2 = hist[t * 4 + 2], s3 = hist[t * 4 + 3];
    int tot = s0 + s1 + s2 + s3;
    tsum[t] = tot;
    __syncthreads();
    for (int off = 1; off < 256; off <<= 1) {
        int v = (t >= off) ? tsum[t - off] : 0;
        __syncthreads();
        tsum[t] += v;
        __syncthreads();
    }
    int pfx = tsum[t] - tot;
    base_l[t * 4]     = pfx;
    base_l[t * 4 + 1] = pfx + s0;
    base_l[t * 4 + 2] = pfx + s0 + s1;
    base_l[t * 4 + 3] = pfx + s0 + s1 + s2;
    cur_l[t * 4]     = base_l[t * 4];
    cur_l[t * 4 + 1] = base_l[t * 4 + 1];
    cur_l[t * 4 + 2] = base_l[t * 4 + 2];
    cur_l[t * 4 + 3] = base_l[t * 4 + 3];
    __syncthreads();

    // one global cursor atomic per nonempty bin
    for (int i = t; i < NBINS; i += 256) {
        int c = hist[i];
        if (c) gbase[i] = atomicAdd(&gcur[i * CSTRIDE], c);
    }
    // scatter into LDS staging (sorted by bin)
    #pragma unroll
    for (int j = 0; j < EPT; ++j) {
        if (ok[j]) {
            int b = (int)((w[j] >> 22) & 0x3ff);
            int p = atomicAdd(&cur_l[b], 1);
            stage[p] = w[j];
        }
    }
    __syncthreads();

    // coalesced run write-out
    int cnt = min(n - c0, CHUNK);
    for (int p = t; p < cnt; p += 256) {
        u64 ww = stage[p];
        int b = (int)((ww >> 22) & 0x3ff);
        int g = gbase[b] + (p - base_l[b]);
        if (g < cap) eg[(size_t)b * cap + g] = ww;
    }
}

// ---------------------------------------------------------------------------
// K2 fused (grid-split):
//   blocks [0, NBINS):    X bins — rowsort in LDS, then SpMM h = X*Wh (fp16 W,
//                         fma_mix accumulate; uint2 gathers = 256 B/edge,
//                         half the previous f32 gather traffic).
//   blocks [NBINS, 2N):   adj bins — rowsort with 512-way key (unchanged).
// ---------------------------------------------------------------------------
__global__ __launch_bounds__(256) void k2_fused(
        const int* __restrict__ gcur_x, const u64* __restrict__ egx,
        const uint2* __restrict__ Wh2, unsigned* __restrict__ hpk,
        const int* __restrict__ gcur_a, const u64* __restrict__ ega,
        unsigned* __restrict__ e4a, int* __restrict__ rptr_a, int* __restrict__ rcnt_a) {
    __shared__ u64 stage[CAPBA];        // 20.8 KB (X path uses first CAPBX)
    __shared__ unsigned sortedx[CAPBX]; // 5.6 KB (X path only)
    __shared__ int hist[SBINS], ptrl[SBINS + 1], curl[SBINS];
    __shared__ int tsum[256];

    int t = threadIdx.x;

    if (blockIdx.x < NBINS) {
        // ================= X path: rowsort(64 keys) + fused SpMM ============
        int bin = blockIdx.x;
        int cnt = min(gcur_x[bin * CSTRIDE], CAPBX);
        size_t base = (size_t)bin * CAPBX;

        for (int i = t; i < cnt; i += 256) stage[i] = egx[base + i];
        if (t < 64) hist[t] = 0;
        __syncthreads();

        for (int i = t; i < cnt; i += 256)
            atomicAdd(&hist[(int)((stage[i] >> 16) & 63)], 1);
        __syncthreads();

        // wave-0 shfl scan over the 64 row counts
        if (t < 64) {
            int v = hist[t];
            int incl = v;
            #pragma unroll
            for (int off = 1; off < 64; off <<= 1) {
                int o = __shfl_up(incl, off, 64);
                if (t >= off) incl += o;
            }
            ptrl[t] = incl - v;
            curl[t] = incl - v;
        }
        __syncthreads();

        for (int i = t; i < cnt; i += 256) {
            u64 w = stage[i];
            int r = (int)((w >> 16) & 63);
            int p = atomicAdd(&curl[r], 1);
            unsigned uv = (unsigned)(w >> 32);
            uv = (uv + 0x7fffu + ((uv >> 16) & 1u)) & 0xffff0000u;
            sortedx[p] = (unsigned)(w & 0xffffu) | uv;
        }
        __syncthreads();

        // fused SpMM: wave wv handles rows wv, wv+4, ... (16 rows each).
        // Half-wave edge split: h = lane>>5 edge parity, l5 = lane&31 picks
        // 4 dims (uint2 of fp16 Wh).  One masked round per 8 edges.
        int lane = t & 63, wv = t >> 6;
        int h = lane >> 5, l5 = lane & 31;
        uint2* hpk2 = (uint2*)hpk;
        for (int r = wv; r < RPB; r += 4) {
            int g = bin * RPB + r;
            if (g >= N_NODES) break;
            int s = ptrl[r];
            int endr = s + hist[r];
            float4 acc = make_float4(0.f, 0.f, 0.f, 0.f);
            for (int eb = s; eb < endr; eb += 8) {
                unsigned u[4];
                #pragma unroll
                for (int k = 0; k < 4; ++k) {
                    int idx = min(eb + k * 2 + h, endr - 1);
                    u[k] = sortedx[idx];
                }
                uint2 a[4];
                #pragma unroll
                for (int k = 0; k < 4; ++k)
                    a[k] = Wh2[(u[k] & 0xffffu) * 32u + (unsigned)l5];
                #pragma unroll
                for (int k = 0; k < 4; ++k) {
                    int idx = eb + k * 2 + h;
                    float v = (idx < endr) ? __uint_as_float(u[k] & 0xffff0000u) : 0.0f;
                    half2v h0 = __builtin_bit_cast(half2v, a[k].x);
                    half2v h1 = __builtin_bit_cast(half2v, a[k].y);
                    acc.x += v * (float)h0.x;
                    acc.y += v * (float)h0.y;
                    acc.z += v * (float)h1.x;
                    acc.w += v * (float)h1.y;
                }
            }
            // combine edge-parity halves
            acc.x += __shfl_xor(acc.x, 32, 64);
            acc.y += __shfl_xor(acc.y, 32, 64);
            acc.z += __shfl_xor(acc.z, 32, 64);
            acc.w += __shfl_xor(acc.w, 32, 64);
            if (h == 0)
                hpk2[(size_t)g * 32 + l5] =
                    make_uint2(pack_f16x2(acc.x, acc.y), pack_f16x2(acc.z, acc.w));
        }
        return;
    }

    // ================= adj path: rowsort with col-phase keys ================
    int bin = blockIdx.x - NBINS;
    int cnt = min(gcur_a[bin * CSTRIDE], CAPBA);
    size_t base = (size_t)bin * CAPBA;

    for (int i = t; i < cnt; i += 256) stage[i] = ega[base + i];
    hist[t] = 0; hist[t + 256] = 0;
    __syncthreads();

    for (int i = t; i < cnt; i += 256) {
        u64 w = stage[i];
        int key = ((int)((w >> 16) & 63) << 3) | ((int)(w & 0xffffu) >> 13);
        atomicAdd(&hist[key], 1);
    }
    __syncthreads();

    // exclusive scan over 512 bins (2/thread + Hillis-Steele)
    int s0 = hist[t * 2], s1 = hist[t * 2 + 1];
    int tot = s0 + s1;
    tsum[t] = tot;
    __syncthreads();
    for (int off = 1; off < 256; off <<= 1) {
        int v = (t >= off) ? tsum[t - off] : 0;
        __syncthreads();
        tsum[t] += v;
        __syncthreads();
    }
    int pfx = tsum[t] - tot;
    ptrl[t * 2]     = pfx;
    ptrl[t * 2 + 1] = pfx + s0;
    curl[t * 2]     = pfx;
    curl[t * 2 + 1] = pfx + s0;
    if (t == 0) ptrl[SBINS] = cnt;
    __syncthreads();

    // scatter DIRECTLY to the bin's global window (10 KB, L2-resident).
    // Values stay bf16-rounded here (edge vals), only h is fp16.
    for (int i = t; i < cnt; i += 256) {
        u64 w = stage[i];
        int key = ((int)((w >> 16) & 63) << 3) | ((int)(w & 0xffffu) >> 13);
        int p = atomicAdd(&curl[key], 1);
        unsigned uv = (unsigned)(w >> 32);
        uv = (uv + 0x7fffu + ((uv >> 16) & 1u)) & 0xffff0000u;
        e4a[base + p] = (unsigned)(w & 0xffffu) | uv;
    }

    if (t < 64) {
        int g = bin * RPB + t;
        if (g < N_NODES) {
            int b0 = ptrl[t * 8];
            rptr_a[g] = (int)base + b0;
            rcnt_a[g] = ptrl[(t + 1) * 8] - b0;   // row contiguous across phases
        }
    }
}

// ---------------------------------------------------------------------------
// SpMM 2 + ReLU: out = relu(A * h).  One wave per row, quarter-wave edge
// split; masked 32-edge rounds (8 gathers in flight).  NEW: fp16 hpk with
// fma_mix accumulate (8 VALU/edge-lane vs 16), 32-bit gather offsets, and
// XCD-bijective block swizzle so a bin's rows share one XCD's L2 phase
// window.
// ---------------------------------------------------------------------------
__global__ __launch_bounds__(256) void spmm_h(
        const int* __restrict__ rptr, const int* __restrict__ rcnt,
        const unsigned* __restrict__ e4,
        const uint4* __restrict__ hpk4, float4* __restrict__ outm,
        int nrows) {
    // bijective XCD swizzle (m204 variant): consecutive swz blocks on one XCD
    int nwg = gridDim.x;
    int qq = nwg >> 3, rr = nwg & 7;
    int xcd = blockIdx.x & 7, ix = blockIdx.x >> 3;
    int swz = (xcd < rr ? xcd * (qq + 1) : rr * (qq + 1) + (xcd - rr) * qq) + ix;

    int wave = (swz * 256 + (int)threadIdx.x) >> 6;
    int lane = threadIdx.x & 63;
    if (wave >= nrows) return;
    int q  = lane >> 4;       // edge slot within a 4-edge group
    int l4 = lane & 15;       // dim group: dims 8*l4 .. 8*l4+7

    int s   = rptr[wave];
    int end = s + rcnt[wave];

    float4 accA = make_float4(0.f, 0.f, 0.f, 0.f);   // dims 8*l4 .. +3
    float4 accB = make_float4(0.f, 0.f, 0.f, 0.f);   // dims 8*l4+4 .. +7

    for (int eb = s; eb < end; eb += 32) {
        unsigned u[8];
        #pragma unroll
        for (int g = 0; g < 8; ++g) {
            int idx = min(eb + g * 4 + q, end - 1);
            u[g] = e4[idx];
        }
        uint4 p[8];
        #pragma unroll
        for (int g = 0; g < 8; ++g)
            p[g] = hpk4[(u[g] & 0xffffu) * 16u + (unsigned)l4];
        #pragma unroll
        for (int g = 0; g < 8; ++g) {
            int idx = eb + g * 4 + q;
            float v = (idx < end) ? __uint_as_float(u[g] & 0xffff0000u) : 0.0f;
            acc_edge(p[g], v, accA, accB);
        }
    }

    // reduce across the 4 quarters (lanes l4, l4+16, l4+32, l4+48)
    #pragma unroll
    for (int m = 16; m <= 32; m <<= 1) {
        accA.x += __shfl_xor(accA.x, m, 64);
        accA.y += __shfl_xor(accA.y, m, 64);
        accA.z += __shfl_xor(accA.z, m, 64);
        accA.w += __shfl_xor(accA.w, m, 64);
        accB.x += __shfl_xor(accB.x, m, 64);
        accB.y += __shfl_xor(accB.y, m, 64);
        accB.z += __shfl_xor(accB.z, m, 64);
        accB.w += __shfl_xor(accB.w, m, 64);
    }
    if (q == 0) {
        accA.x = fmaxf(accA.x, 0.f); accA.y = fmaxf(accA.y, 0.f);
        accA.z = fmaxf(accA.z, 0.f); accA.w = fmaxf(accA.w, 0.f);
        accB.x = fmaxf(accB.x, 0.f); accB.y = fmaxf(accB.y, 0.f);
        accB.z = fmaxf(accB.z, 0.f); accB.w = fmaxf(accB.w, 0.f);
        size_t o = (size_t)wave * 32 + 2 * l4;
        outm[o]     = accA;
        outm[o + 1] = accB;
    }
}

extern "C" void kernel_launch(void* const* d_in, const int* in_sizes, int n_in,
                              void* d_out, int out_size, void* d_ws, size_t ws_size,
                              hipStream_t stream) {
    const int*   x_rows     = (const int*)d_in[0];
    const int*   x_cols     = (const int*)d_in[1];
    const float* x_vals     = (const float*)d_in[2];
    const float* drop_noise = (const float*)d_in[3];
    const int*   adj_rows   = (const int*)d_in[4];
    const int*   adj_cols   = (const int*)d_in[5];
    const float* adj_vals   = (const float*)d_in[6];
    const float* W          = (const float*)d_in[7];

    const int nnz = in_sizes[0];   // 800000
    const int ne  = in_sizes[4];   // 1600000

    float* out = (float*)d_out;

    // ---- workspace layout (~46 MB) -----------------------------------------
    char* base = (char*)d_ws;
    unsigned* hpk = (unsigned*)base;                                    // 12.8 MB
    u64* egx = (u64*)(base + (size_t)N_NODES * OD2 * sizeof(unsigned)); // 8.8 MB
    u64* ega = egx + (size_t)NBINS * CAPBX;                             // 16.3 MB
    unsigned* e4a = (unsigned*)(ega + (size_t)NBINS * CAPBA);           // 8.1 MB
    int* rptr_a = (int*)(e4a + (size_t)NBINS * CAPBA);                  // 200 KB
    int* rcnt_a = rptr_a + N_NODES;
    int* gcur_x = rcnt_a + N_NODES;                                     // 25 KB
    int* gcur_a = gcur_x + NBINS * CSTRIDE;
    unsigned* Wh = (unsigned*)(gcur_a + NBINS * CSTRIDE);               // 64 KB fp16 W

    hipMemsetAsync(gcur_x, 0, 2 * (size_t)NBINS * CSTRIDE * sizeof(int), stream);

    const int BXC = (nnz + CHUNK - 1) / CHUNK;   // 196
    const int BAC = (ne + CHUNK - 1) / CHUNK;    // 391
    const int BSPH = (N_NODES * 64 + 255) / 256; // 12500

    // L1: bin partition (+ last block converts W -> fp16)
    partition<<<BXC + BAC + 1, 256, 0, stream>>>(
        x_rows, x_cols, x_vals, drop_noise, nnz,
        adj_rows, adj_cols, adj_vals, ne,
        gcur_x, egx, gcur_a, ega, BXC,
        (const float2*)W, Wh);

    // K2: X rowsort+SpMM fused (fp16 W)  ||  adj rowsort (independent)
    k2_fused<<<2 * NBINS, 256, 0, stream>>>(
        gcur_x, egx, (const uint2*)Wh, hpk,
        gcur_a, ega, e4a, rptr_a, rcnt_a);

    // K3: out = relu(A * h)
    spmm_h<<<BSPH, 256, 0, stream>>>(rptr_a, rcnt_a, e4a,
                                     (const uint4*)hpk, (float4*)out, N_NODES);
}